// Round 8
// baseline (449.399 us; speedup 1.0000x reference)
//
#include <hip/hip_runtime.h>
#include <hip/hip_cooperative_groups.h>
namespace cg = cooperative_groups;

#define HH 512
#define WW 1024
#define HWSZ (HH*WW)
#define NCLS 19
#define KEEP 128
#define CTHR 0.1f
#define NBLK 512            // nms tiles = (WW/64)*(HH/16)
#define NRED 16
#define SEGPB 32
#define GRID 768
typedef unsigned long long u64;

static __device__ __forceinline__ void bitonic_desc(u64* b, int m, int tid) {
    for (int kk = 2; kk <= m; kk <<= 1) {
        for (int j = kk >> 1; j; j >>= 1) {
            for (int i = tid; i < m; i += 256) {
                int ixj = i ^ j;
                if (ixj > i) {
                    bool desc = ((i & kk) == 0);
                    u64 a = b[i], c = b[ixj];
                    if ((a < c) == desc) { b[i] = c; b[ixj] = a; }
                }
            }
            __syncthreads();
        }
    }
}

// LDS overlay (33088 B):
//  nms:    sin_[22*70] @0 (6160) | shm[22*64] @6160 (5632) | lkeys[1024] @11792 (8192)
//  reduce: buf[2048] @0 (16384) | scnt[32] @16384
//  select: buf[2048] @0 | buf2[1024] @16384 (8192) | hist[2048] @24576 (8192) | seg[64] @32768
//  assign: slog[4864] @0 (19456) | sc[128] @19456 (2048) | skept[128] @21504 (2048) | skidx[128] @23552
__global__ void __launch_bounds__(256, 3) fused_kernel(
        const float* __restrict__ logits, const float* __restrict__ heat,
        const float* __restrict__ offs, const int* __restrict__ thing_ids, int n_thing,
        float* __restrict__ out, u64* __restrict__ keys, int* __restrict__ blkcnt,
        u64* __restrict__ gtop, float4* __restrict__ centers, int maxpb)
{
    cg::grid_group gg = cg::this_grid();
    __shared__ __align__(16) char smem[33088];
    __shared__ int s_lcnt, s_bin, s_above, s_cnt2, s_nz, s_nkept;
    __shared__ float sred[16];
    __shared__ float ured[4];
    __shared__ int wcnt[4];
    __shared__ int sids[32];

    int tid = threadIdx.x;
    int lane = tid & 63, wid = tid >> 6;
    u64 lmask_lt = (1ull << lane) - 1ull;

    // ================= Phase 1: NMS (blocks 0..511) =================
    if (blockIdx.x < NBLK) {
        float* sin_ = (float*)smem;            // [22][70]
        float* shm  = (float*)(smem + 6160);   // [22][64]
        u64*   lk   = (u64*)(smem + 11792);    // [1024]
        if (tid == 0) s_lcnt = 0;
        int bx = blockIdx.x & 15, by = blockIdx.x >> 4;
        int ox = bx * 64, oy = by * 16;

        for (int i = tid; i < 22 * 70; i += 256) {
            int ly = i / 70, lx = i % 70;
            int gy = oy + ly - 3, gx = ox + lx - 3;
            float v = 0.f;
            if (gy >= 0 && gy < HH && gx >= 0 && gx < WW) {
                float t = heat[gy * WW + gx];
                v = (t > CTHR) ? t : 0.f;
            }
            sin_[i] = v;
        }
        __syncthreads();
        for (int i = tid; i < 22 * 64; i += 256) {
            int ly = i >> 6, lx = i & 63;
            float m = sin_[ly * 70 + lx];
#pragma unroll
            for (int d = 1; d < 7; d++) m = fmaxf(m, sin_[ly * 70 + lx + d]);
            shm[i] = m;
        }
        __syncthreads();
        for (int i = tid; i < 16 * 64; i += 256) {
            int ly = i >> 6, lx = i & 63;
            float m = shm[i];
#pragma unroll
            for (int d = 1; d < 7; d++) m = fmaxf(m, shm[(ly + d) * 64 + lx]);
            float c = sin_[(ly + 3) * 70 + lx + 3];
            float o = (m == c) ? c : 0.f;
            int gy = oy + ly, gx = ox + lx;
            out[HWSZ + gy * WW + gx] = o;
            if (o > 0.f) {
                int pos = atomicAdd(&s_lcnt, 1);
                lk[pos] = ((u64)__float_as_uint(o) << 32) |
                          (u64)(0xFFFFFFFFu - (unsigned)(gy * WW + gx));
            }
        }
        __syncthreads();
        int n = s_lcnt < maxpb ? s_lcnt : maxpb;
        if (tid == 0) blkcnt[blockIdx.x] = n;
        for (int i = tid; i < n; i += 256)
            keys[(size_t)i * NBLK + blockIdx.x] = lk[i];
    }
    __threadfence();
    gg.sync();

    // ================= Phase 2: per-group top-128 (blocks 0..15) =================
    if (blockIdx.x < NRED) {
        u64* buf  = (u64*)smem;
        int* scnt = (int*)(smem + 16384);
        int g0 = blockIdx.x * SEGPB;
        if (tid < SEGPB) {
            int c = blkcnt[g0 + tid];
            scnt[tid] = c < 0 ? 0 : (c > maxpb ? maxpb : c);
        }
        if (tid == 0) s_lcnt = 0;
        __syncthreads();
        int mx = 0;
        for (int j = 0; j < SEGPB; j++) { int c = scnt[j]; mx = c > mx ? c : mx; }
        int total = SEGPB * mx;
        int base = 0;
        do {
            int wend = base + 1792 < total ? base + 1792 : total;
            for (int ii = 0; ii < 7; ii++) {
                int i = base + ii * 256 + tid;
                int sg = i & 31, sl = i >> 5;
                bool pv = (i < wend) && (sl < scnt[sg]);
                u64 kv = pv ? keys[(size_t)sl * NBLK + (g0 + sg)] : 0ull;
                u64 mask = __ballot(pv);
                if (mask) {
                    int leader = __builtin_ctzll(mask);
                    int bpos = 0;
                    if (lane == leader) bpos = atomicAdd(&s_lcnt, (int)__popcll(mask));
                    bpos = __shfl(bpos, leader);
                    if (pv) buf[bpos + (int)__popcll(mask & lmask_lt)] = kv;
                }
            }
            __syncthreads();
            int n = s_lcnt;
            int m = 256; while (m < n) m <<= 1;
            for (int i = tid; i < m; i += 256) if (i >= n) buf[i] = 0ull;
            __syncthreads();
            bitonic_desc(buf, m, tid);
            if (tid == 0) s_lcnt = n < KEEP ? n : KEEP;
            base += 1792;
            __syncthreads();
        } while (base < total);
        if (tid < KEEP) gtop[blockIdx.x * KEEP + tid] = buf[tid];
    }
    __threadfence();
    gg.sync();

    // ================= Phase 3: global select (block 0) =================
    if (blockIdx.x == 0) {
        u64* buf  = (u64*)smem;
        u64* buf2 = (u64*)(smem + 16384);
        unsigned* hist = (unsigned*)(smem + 24576);
        unsigned* seg  = (unsigned*)(smem + 32768);
        if (tid == 0) { s_cnt2 = 0; s_nz = 0; }
        for (int i = tid; i < 2048; i += 256) hist[i] = 0;
        __syncthreads();
        int mynz = 0;
        for (int i = tid; i < 2048; i += 256) {
            u64 kv = gtop[i];
            buf[i] = kv;
            mynz += (kv != 0ull);
        }
        for (int d = 32; d; d >>= 1) mynz += __shfl_xor(mynz, d);
        if (lane == 0) atomicAdd(&s_nz, mynz);
        __syncthreads();
        int K = s_nz < KEEP ? s_nz : KEEP;

        // pass 1: top 11 bits (wave-aggregated; values concentrate in one bin)
        for (int ii = 0; ii < 8; ii++) {
            int bin = (int)(buf[ii * 256 + tid] >> 53);
            u64 remaining = ~0ull;
            while (remaining) {
                int leader = __builtin_ctzll(remaining);
                int lb = __shfl(bin, leader);
                u64 matches = __ballot(bin == lb) & remaining;
                if (lane == leader) atomicAdd(&hist[lb], (unsigned)__popcll(matches));
                remaining &= ~matches;
            }
        }
        __syncthreads();
        if (tid < 64) { unsigned ss = 0; for (int i = 0; i < 32; i++) ss += hist[tid * 32 + i]; seg[tid] = ss; }
        __syncthreads();
        if (tid == 0) {
            int acc = 0, B = 0;
            if (K > 0) {
                for (int sgi = 63; sgi >= 0; sgi--) {
                    if (acc + (int)seg[sgi] >= K) {
                        for (int b = sgi * 32 + 31;; b--) {
                            if (acc + (int)hist[b] >= K) { B = b; break; }
                            acc += hist[b];
                        }
                        break;
                    }
                    acc += seg[sgi];
                }
            }
            s_bin = B; s_above = acc;
        }
        __syncthreads();
        int B1 = s_bin, K2 = K - s_above;
        __syncthreads();
        for (int i = tid; i < 2048; i += 256) hist[i] = 0;
        __syncthreads();

        // pass 2: bits [52:42] within bin B1 (mantissa-spread -> direct atomics)
        for (int ii = 0; ii < 8; ii++) {
            u64 kv = buf[ii * 256 + tid];
            if ((unsigned)(kv >> 53) == (unsigned)B1)
                atomicAdd(&hist[(unsigned)((kv >> 42) & 2047u)], 1u);
        }
        __syncthreads();
        if (tid < 64) { unsigned ss = 0; for (int i = 0; i < 32; i++) ss += hist[tid * 32 + i]; seg[tid] = ss; }
        __syncthreads();
        if (tid == 0) {
            int acc = 0, B = 0;
            if (K2 > 0) {
                for (int sgi = 63; sgi >= 0; sgi--) {
                    if (acc + (int)seg[sgi] >= K2) {
                        for (int b = sgi * 32 + 31;; b--) {
                            if (acc + (int)hist[b] >= K2) { B = b; break; }
                            acc += hist[b];
                        }
                        break;
                    }
                    acc += seg[sgi];
                }
            }
            s_bin = B;
        }
        __syncthreads();
        u64 cutPrefix = (((u64)B1 << 11) | (u64)s_bin);

        // collect >= cutoff (wave-aggregated push)
        for (int ii = 0; ii < 8; ii++) {
            u64 kv = buf[ii * 256 + tid];
            bool want = (kv >> 42) >= cutPrefix && kv != 0ull;
            u64 mask = __ballot(want);
            if (mask) {
                int leader = __builtin_ctzll(mask);
                int bpos = 0;
                if (lane == leader) bpos = atomicAdd(&s_cnt2, (int)__popcll(mask));
                bpos = __shfl(bpos, leader);
                if (want) {
                    int pos = bpos + (int)__popcll(mask & lmask_lt);
                    if (pos < 1024) buf2[pos] = kv;
                }
            }
        }
        __syncthreads();
        int n = s_cnt2; if (n > 1024) n = 1024;
        int m = 256; while (m < n) m <<= 1;
        for (int i = tid; i < m; i += 256) if (i >= n) buf2[i] = 0ull;
        __syncthreads();
        bitonic_desc(buf2, m, tid);

        if (tid < KEEP) {
            u64 k64 = buf2[tid];
            float sc_, cy, cx, a;
            if (k64 == 0ull) { sc_ = 0.f; cy = 0.f; cx = 0.f; a = 0.f; }
            else {
                sc_ = __uint_as_float((unsigned)(k64 >> 32));
                unsigned idx = 0xFFFFFFFFu - (unsigned)(k64 & 0xFFFFFFFFu);
                cy = (float)(idx / WW);
                cx = (float)(idx % WW);
                a = cy * cy + cx * cx;              // exact (< 2^24)
            }
            centers[tid] = make_float4(cy, cx, a, sc_);
        }
    }
    __threadfence();
    gg.sync();

    // ================= Phase 4: assign (all blocks, 2048 tiles) =================
    {
        float*  slog  = (float*)smem;               // [4864]
        float4* sc    = (float4*)(smem + 19456);    // [128]
        float4* skept = (float4*)(smem + 21504);    // [128]
        int*    skidx = (int*)(smem + 23552);       // [128]
        if (tid < KEEP) sc[tid] = centers[tid];
        if (tid < n_thing) sids[tid] = thing_ids[tid];

        for (int t = blockIdx.x; t < 2048; t += gridDim.x) {
            __syncthreads();                        // protect LDS reuse across iterations
            int bx = t & 63, by = t >> 6;
            int lr = tid >> 4, lc = tid & 15;
            int gy = by * 16 + lr, gx = bx * 16 + lc;
            int p = gy * WW + gx;

            const float4* src4 = (const float4*)(logits + ((size_t)(by * 16) * WW + bx * 16) * NCLS);
            float4* dst4 = (float4*)slog;
            for (int i = tid; i < 16 * 76; i += 256) {
                int r = i / 76, c = i % 76;
                dst4[i] = src4[(size_t)r * 4864 + c];
            }

            float2 off2 = ((const float2*)offs)[p];
            float py = __fadd_rn((float)gy, off2.x);
            float px = __fadd_rn((float)gx, off2.y);

            float ymn = py, ymx = py, xmn = px, xmx = px;
            for (int d = 32; d; d >>= 1) {
                ymn = fminf(ymn, __shfl_xor(ymn, d));
                ymx = fmaxf(ymx, __shfl_xor(ymx, d));
                xmn = fminf(xmn, __shfl_xor(xmn, d));
                xmx = fmaxf(xmx, __shfl_xor(xmx, d));
            }
            if (lane == 0) {
                sred[wid * 4 + 0] = ymn; sred[wid * 4 + 1] = ymx;
                sred[wid * 4 + 2] = xmn; sred[wid * 4 + 3] = xmx;
            }
            __syncthreads();

            ymn = fminf(fminf(sred[0], sred[4]), fminf(sred[8],  sred[12]));
            ymx = fmaxf(fmaxf(sred[1], sred[5]), fmaxf(sred[9],  sred[13]));
            xmn = fminf(fminf(sred[2], sred[6]), fminf(sred[10], sred[14]));
            xmx = fmaxf(fmaxf(sred[3], sred[7]), fmaxf(sred[11], sred[15]));

            float L = INFINITY, U = INFINITY;
            bool valid = false;
            if (tid < KEEP) {
                float4 c4 = sc[tid];
                valid = (c4.w > 0.f);
                if (valid) {
                    float dyl = fmaxf(fmaxf(ymn - c4.x, c4.x - ymx), 0.f);
                    float dxl = fmaxf(fmaxf(xmn - c4.y, c4.y - xmx), 0.f);
                    L = dyl * dyl + dxl * dxl;
                    float dyu = fmaxf(fabsf(c4.x - ymn), fabsf(c4.x - ymx));
                    float dxu = fmaxf(fabsf(c4.y - xmn), fabsf(c4.y - xmx));
                    U = dyu * dyu + dxu * dxu;
                }
            }
            float u = U;
            for (int d = 32; d; d >>= 1) u = fminf(u, __shfl_xor(u, d));
            if (lane == 0) ured[wid] = u;
            __syncthreads();
            float Umin = fminf(fminf(ured[0], ured[1]), fminf(ured[2], ured[3]));

            bool keep = valid && (L <= Umin + 8.0f);   // margin 8 >> rounding slop ~2
            u64 mask = __ballot(keep);
            int prefix = __popcll(mask & lmask_lt);
            if (lane == 0) wcnt[wid] = __popcll(mask);
            __syncthreads();
            int base = (wid == 1) ? wcnt[0] : 0;
            if (keep) { skept[base + prefix] = sc[tid]; skidx[base + prefix] = tid; }
            if (tid == 0) s_nkept = wcnt[0] + wcnt[1];
            __syncthreads();

            const float* l = slog + tid * NCLS;        // odd stride -> 2-way LDS alias, free
            float best = l[0];
            int cls = 0;
#pragma unroll
            for (int c = 1; c < NCLS; c++) {
                float v = l[c];
                if (v > best) { best = v; cls = c; }
            }
            bool thing = false;
            for (int j = 0; j < n_thing; j++) thing = thing || (cls == sids[j]);

            float b = __fadd_rn(__fmul_rn(py, py), __fmul_rn(px, px));

            float bestd = INFINITY;
            int bi = -1;
            int nk = s_nkept;
            for (int k = 0; k < nk; k++) {
                float4 c4 = skept[k];
                // replicate f32 gemm: m = fma(cx,px, rn(cy*py)); d2 = rn(rn(a-2m)+b)
                float m  = __fmaf_rn(c4.y, px, __fmul_rn(c4.x, py));
                float d2 = __fadd_rn(__fsub_rn(c4.z, __fadd_rn(m, m)), b);
                if (d2 < bestd) { bestd = d2; bi = k; }
            }

            float inst, smap;
            if (bi < 0) { inst = thing ? 1.f : 0.f; smap = 0.f; }
            else {
                inst = thing ? (float)(skidx[bi] + 1) : 0.f;
                smap = thing ? skept[bi].w : 0.f;
            }
            out[p] = inst;
            out[2 * HWSZ + p] = smap;
            out[3 * HWSZ + p] = (float)cls;
        }
    }
}

extern "C" void kernel_launch(void* const* d_in, const int* in_sizes, int n_in,
                              void* d_out, int out_size, void* d_ws, size_t ws_size,
                              hipStream_t stream) {
    const float* logits = (const float*)d_in[0];
    const float* heat   = (const float*)d_in[1];
    const float* offs   = (const float*)d_in[2];
    const int*   tids   = (const int*)d_in[3];
    int n_thing = in_sizes[3];
    if (n_thing > 32) n_thing = 32;

    float* out = (float*)d_out;
    char* ws = (char*)d_ws;
    int* blkcnt = (int*)ws;                                  // 2 KB
    float4* centers = (float4*)(ws + 4096);                  // 2 KB
    u64* gtop = (u64*)(ws + 8192);                           // 16 KB
    long long avail = (long long)ws_size - 32768;
    int maxpb = (int)(avail / (NBLK * 8));
    if (maxpb > 120) maxpb = 120;
    if (maxpb < 16) maxpb = 16;
    u64* keys = (u64*)(ws + 32768);                          // transposed [maxpb][512]

    void* args[] = { (void*)&logits, (void*)&heat, (void*)&offs, (void*)&tids,
                     (void*)&n_thing, (void*)&out, (void*)&keys, (void*)&blkcnt,
                     (void*)&gtop, (void*)&centers, (void*)&maxpb };
    hipLaunchCooperativeKernel((const void*)fused_kernel, dim3(GRID), dim3(256),
                               args, 0, stream);
}

// Round 9
// 47.573 us; speedup vs baseline: 9.4466x; 9.4466x over previous
//
#include <hip/hip_runtime.h>

#define HH 512
#define WW 1024
#define HWSZ (HH*WW)
#define NCLS 19
#define KEEP 128
#define CTHR 0.1f
#define NBLK 512            // nms tiles = (WW/64)*(HH/16)
#define NRED 16
#define SEGPB 32
#define GSLOT 192           // candidate slots per reduce block
typedef unsigned long long u64;

// monotone value->bin map, fine resolution where the data lives (v in [0.5,1))
static __device__ __forceinline__ int key_bin(u64 k) {
    unsigned u = (unsigned)(k >> 32);
    if (u >= 0x3F000000u) {
        int b = 4096 + (int)((u - 0x3F000000u) >> 11);
        return b > 8191 ? 8191 : b;
    }
    return (int)(u >> 19);   // < 2016
}

// wave-aggregated LDS push; trip counts must be wave-uniform at call sites
static __device__ __forceinline__ int lds_push(int* cnt, bool want, int lane, u64 lmask_lt) {
    u64 mask = __ballot(want);
    int pos = -1;
    if (mask) {
        int leader = __builtin_ctzll(mask);
        int bpos = 0;
        if (lane == leader) bpos = atomicAdd(cnt, (int)__popcll(mask));
        bpos = __shfl(bpos, leader);
        if (want) pos = bpos + (int)__popcll(mask & lmask_lt);
    }
    return pos;
}

// generic LDS bitonic, descending, m = pow2
static __device__ __forceinline__ void bitonic_lds(u64* b, int m, int tid) {
    for (int kk = 2; kk <= m; kk <<= 1) {
        for (int j = kk >> 1; j; j >>= 1) {
            for (int i = tid; i < m; i += 256) {
                int ixj = i ^ j;
                if (ixj > i) {
                    bool desc = ((i & kk) == 0);
                    u64 a = b[i], c = b[ixj];
                    if ((a < c) == desc) { b[i] = c; b[ixj] = a; }
                }
            }
            __syncthreads();
        }
    }
}

// 256-element descending bitonic, 1 elem/thread: shfl for j<64, LDS for j>=64
static __device__ __forceinline__ void bitonic256_reg(u64* ov, int tid) {
    u64 a = ov[tid];
    __syncthreads();
    for (int kk = 2; kk <= 256; kk <<= 1) {
        bool desc = ((tid & kk) == 0);
        for (int j = kk >> 1; j; j >>= 1) {
            u64 b;
            if (j >= 64) {
                ov[tid] = a; __syncthreads();
                b = ov[tid ^ j]; __syncthreads();
            } else {
                b = __shfl_xor(a, j);
            }
            bool up = ((tid & j) == 0);
            bool keepMax = (up == desc);
            a = keepMax ? (a > b ? a : b) : (a < b ? a : b);
        }
    }
    ov[tid] = a;
    __syncthreads();
}

// find cutoff bin: largest cb with count(bins>cb) < K <= count(bins>=cb).
// hist[8192], cs[256] scratch; returns via s_bin (8192 if K<=0). All-thread call.
static __device__ __forceinline__ void find_cutoff(unsigned* hist, unsigned* cs, int K,
                                                   int tid, int* s_bin, int* s_chunk, unsigned* s_cabove) {
    if (tid == 0) { *s_bin = 8192; *s_chunk = -1; }
    unsigned c = 0;
    for (int i = 0; i < 32; i++) c += hist[tid * 32 + i];
    cs[tid] = c;
    __syncthreads();
    for (int d = 1; d < 256; d <<= 1) {           // inclusive suffix sums
        unsigned v = cs[tid];
        unsigned w = (tid + d < 256) ? cs[tid + d] : 0u;
        __syncthreads();
        cs[tid] = v + w;
        __syncthreads();
    }
    unsigned above = (tid < 255) ? cs[tid + 1] : 0u;
    unsigned incl = cs[tid];
    if (K > 0 && above < (unsigned)K && (unsigned)K <= incl) { *s_chunk = tid; *s_cabove = above; }
    __syncthreads();
    if (tid < 64 && *s_chunk >= 0) {
        int ch = *s_chunk;
        unsigned v = (tid < 32) ? hist[ch * 32 + tid] : 0u;
        unsigned s = v;
        for (int d = 1; d < 64; d <<= 1) {
            unsigned o = __shfl_down(s, d);
            if (tid + d < 64) s += o;
        }
        unsigned ab = *s_cabove + (s - v);
        if (tid < 32 && ab < (unsigned)K && (unsigned)K <= *s_cabove + s)
            *s_bin = ch * 32 + tid;
    }
    __syncthreads();
}

// ---------------- NMS (7x7, SAME) -> transposed per-block survivor segments ----------------
__global__ void nms_kernel(const float* __restrict__ hm_in, float* __restrict__ hm_out,
                           u64* __restrict__ keys, int* __restrict__ blkcnt, int maxpb)
{
    const int TX = 64, TY = 16;
    __shared__ float sin_[TY + 6][TX + 6];
    __shared__ float shm[TY + 6][TX];
    __shared__ u64 lkeys[TX * TY];
    __shared__ int lcnt;

    if (threadIdx.x == 0) lcnt = 0;
    int bx = blockIdx.x & 15, by = blockIdx.x >> 4;
    int ox = bx * TX, oy = by * TY;

    for (int i = threadIdx.x; i < (TY + 6) * (TX + 6); i += blockDim.x) {
        int ly = i / (TX + 6), lx = i % (TX + 6);
        int gy = oy + ly - 3, gx = ox + lx - 3;
        float v = 0.f;
        if (gy >= 0 && gy < HH && gx >= 0 && gx < WW) {
            float t = hm_in[gy * WW + gx];
            v = (t > CTHR) ? t : 0.f;
        }
        sin_[ly][lx] = v;
    }
    __syncthreads();
    for (int i = threadIdx.x; i < (TY + 6) * TX; i += blockDim.x) {
        int ly = i / TX, lx = i % TX;
        float m = sin_[ly][lx];
#pragma unroll
        for (int d = 1; d < 7; d++) m = fmaxf(m, sin_[ly][lx + d]);
        shm[ly][lx] = m;
    }
    __syncthreads();
    for (int i = threadIdx.x; i < TY * TX; i += blockDim.x) {
        int ly = i / TX, lx = i % TX;
        float m = shm[ly][lx];
#pragma unroll
        for (int d = 1; d < 7; d++) m = fmaxf(m, shm[ly + d][lx]);
        float c = sin_[ly + 3][lx + 3];
        float o = (m == c) ? c : 0.f;
        int gy = oy + ly, gx = ox + lx;
        hm_out[gy * WW + gx] = o;
        if (o > 0.f) {
            int pos = atomicAdd(&lcnt, 1);
            lkeys[pos] = ((u64)__float_as_uint(o) << 32) |
                         (u64)(0xFFFFFFFFu - (unsigned)(gy * WW + gx));
        }
    }
    __syncthreads();
    int n = lcnt < maxpb ? lcnt : maxpb;
    if (threadIdx.x == 0) blkcnt[blockIdx.x] = n;
    for (int i = threadIdx.x; i < n; i += blockDim.x)
        keys[(size_t)i * NBLK + blockIdx.x] = lkeys[i];
}

// ---------------- reduce: 16 blocks, hist-narrow each group of 32 segments to <=192 cands ----
__global__ void __launch_bounds__(256) reduce_kernel(const u64* __restrict__ keys,
                                                     const int* __restrict__ blkcnt, int maxpb,
                                                     u64* __restrict__ gtop, int* __restrict__ gcnt)
{
    __shared__ __align__(16) char smem[64512];
    u64* kbuf = (u64*)smem;                      // 3840 keys
    unsigned* hist = (unsigned*)(smem + 30720);  // 8192 bins (overlay: ov 4096 u64)
    u64* ov = (u64*)(smem + 30720);
    unsigned* cs = (unsigned*)(smem + 63488);    // 256
    __shared__ int scnt[SEGPB];
    __shared__ int s_n, s_m, s_bin, s_chunk;
    __shared__ unsigned s_cabove;

    int tid = threadIdx.x, lane = tid & 63;
    u64 lmask_lt = (1ull << lane) - 1ull;
    int g0 = blockIdx.x * SEGPB;

    if (tid < SEGPB) {
        int c = blkcnt[g0 + tid];
        scnt[tid] = c < 0 ? 0 : (c > maxpb ? maxpb : c);
    }
    if (tid == 0) { s_n = 0; s_m = 0; }
    {   // zero hist via uint4
        uint4* h4 = (uint4*)hist;
        for (int i = tid; i < 2048; i += 256) h4[i] = make_uint4(0, 0, 0, 0);
    }
    __syncthreads();
    int mxc = 0;
    for (int j = 0; j < SEGPB; j++) { int c = scnt[j]; mxc = c > mxc ? c : mxc; }

    // load + compact into kbuf (coalesced, wave-aggregated positions)
    int iters = (SEGPB * mxc + 255) >> 8;
    for (int it = 0; it < iters; ++it) {
        int i = it * 256 + tid;
        int sg = i & (SEGPB - 1), sl = i >> 5;
        bool pv = (sl < scnt[sg]);
        u64 kv = pv ? keys[(size_t)sl * NBLK + (g0 + sg)] : 0ull;
        int pos = lds_push(&s_n, pv, lane, lmask_lt);
        if (pv) kbuf[pos] = kv;
    }
    __syncthreads();
    int tcnt = s_n;
    int K = tcnt < KEEP ? tcnt : KEEP;

    // hist (bins are spread: ~1-3 keys/bin near the top)
    for (int i = tid; i < tcnt; i += 256) atomicAdd(&hist[key_bin(kbuf[i])], 1u);
    __syncthreads();

    find_cutoff(hist, cs, K, tid, &s_bin, &s_chunk, &s_cabove);
    int cb = s_bin;

    // collect keys with bin >= cb into ov (hist dead from here)
    int citers = (tcnt + 255) >> 8;
    for (int it = 0; it < citers; ++it) {
        int i = it * 256 + tid;
        bool want = (i < tcnt) && key_bin(kbuf[i]) >= cb;
        int pos = lds_push(&s_m, want, lane, lmask_lt);
        if (want) ov[pos] = kbuf[i];
    }
    __syncthreads();
    int n = s_m;
    if (n <= GSLOT) {
        if (tid == 0) gcnt[blockIdx.x] = n;
        for (int i = tid; i < n; i += 256) gtop[blockIdx.x * GSLOT + i] = ov[i];
    } else {                                   // tie-heavy fallback: exact top-128 sorted
        int m = 256; while (m < n) m <<= 1;    // n <= 3840 -> m <= 4096 (32KB, fits overlay)
        for (int i = tid; i < m; i += 256) if (i >= n) ov[i] = 0ull;
        __syncthreads();
        if (m == 256) bitonic256_reg(ov, tid); else bitonic_lds(ov, m, tid);
        if (tid == 0) gcnt[blockIdx.x] = KEEP;
        if (tid < KEEP) gtop[blockIdx.x * GSLOT + tid] = ov[tid];
    }
}

// ---------------- select: 1 block, hist-narrow 16x<=192 candidates -> sorted top-128 --------
__global__ void __launch_bounds__(256) select_kernel(const u64* __restrict__ gtop,
                                                     const int* __restrict__ gcnt,
                                                     float4* __restrict__ centers)
{
    __shared__ __align__(16) char smem[58368];
    u64* kbuf = (u64*)smem;                      // 3072 keys
    unsigned* hist = (unsigned*)(smem + 24576);  // 8192 bins (overlay: ov 4096 u64)
    u64* ov = (u64*)(smem + 24576);
    unsigned* cs = (unsigned*)(smem + 57344);    // 256
    __shared__ int scnt[NRED];
    __shared__ int s_n, s_m, s_bin, s_chunk;
    __shared__ unsigned s_cabove;

    int tid = threadIdx.x, lane = tid & 63;
    u64 lmask_lt = (1ull << lane) - 1ull;

    if (tid < NRED) {
        int c = gcnt[tid];
        scnt[tid] = c < 0 ? 0 : (c > GSLOT ? GSLOT : c);
    }
    if (tid == 0) { s_n = 0; s_m = 0; }
    {
        uint4* h4 = (uint4*)hist;
        for (int i = tid; i < 2048; i += 256) h4[i] = make_uint4(0, 0, 0, 0);
    }
    __syncthreads();

    // load + compact 16*192 slots
    for (int it = 0; it < (NRED * GSLOT) / 256; ++it) {
        int i = it * 256 + tid;
        int b = i / GSLOT, j = i % GSLOT;
        bool pv = (j < scnt[b]);
        u64 kv = pv ? gtop[i] : 0ull;
        int pos = lds_push(&s_n, pv, lane, lmask_lt);
        if (pv) kbuf[pos] = kv;
    }
    __syncthreads();
    int tcnt = s_n;
    int K = tcnt < KEEP ? tcnt : KEEP;

    for (int i = tid; i < tcnt; i += 256) atomicAdd(&hist[key_bin(kbuf[i])], 1u);
    __syncthreads();

    find_cutoff(hist, cs, K, tid, &s_bin, &s_chunk, &s_cabove);
    int cb = s_bin;

    int citers = (tcnt + 255) >> 8;
    for (int it = 0; it < citers; ++it) {
        int i = it * 256 + tid;
        bool want = (i < tcnt) && key_bin(kbuf[i]) >= cb;
        int pos = lds_push(&s_m, want, lane, lmask_lt);
        if (want) ov[pos] = kbuf[i];
    }
    __syncthreads();
    int n = s_m;                                 // typically ~131, <= 3072
    int m = 256; while (m < n) m <<= 1;
    for (int i = tid; i < m; i += 256) if (i >= n) ov[i] = 0ull;
    __syncthreads();
    if (m == 256) bitonic256_reg(ov, tid); else bitonic_lds(ov, m, tid);

    if (tid < KEEP) {
        u64 k64 = ov[tid];
        float sc_, cy, cx, a;
        if (k64 == 0ull) { sc_ = 0.f; cy = 0.f; cx = 0.f; a = 0.f; }
        else {
            sc_ = __uint_as_float((unsigned)(k64 >> 32));
            unsigned idx = 0xFFFFFFFFu - (unsigned)(k64 & 0xFFFFFFFFu);
            cy = (float)(idx / WW);
            cx = (float)(idx % WW);
            a = cy * cy + cx * cx;               // exact (< 2^24)
        }
        centers[tid] = make_float4(cy, cx, a, sc_);
    }
}

// ---------------- fused argmax + thing mask + PRUNED nearest-center assignment ----------------
__global__ void __launch_bounds__(256) assign_kernel(
        const float* __restrict__ logits, const float* __restrict__ offs,
        const int* __restrict__ thing_ids, int n_thing,
        const float4* __restrict__ centers, float* __restrict__ out)
{
    __shared__ float4 sc[KEEP];
    __shared__ float4 skept[KEEP];
    __shared__ int   skidx[KEEP];
    __shared__ float slog[256 * NCLS];
    __shared__ float sred[16];
    __shared__ float ured[4];
    __shared__ int   wcnt[4];
    __shared__ int   s_nkept;
    __shared__ int   sids[32];

    int tid = threadIdx.x;
    if (tid < KEEP) sc[tid] = centers[tid];
    if (tid < n_thing) sids[tid] = thing_ids[tid];

    int bx = blockIdx.x & 63;
    int by = blockIdx.x >> 6;
    int lr = tid >> 4, lc = tid & 15;
    int gy = by * 16 + lr, gx = bx * 16 + lc;
    int p  = gy * WW + gx;

    {
        const float4* src4 = (const float4*)(logits + ((size_t)(by * 16) * WW + bx * 16) * NCLS);
        float4* dst4 = (float4*)slog;
        for (int i = tid; i < 16 * 76; i += 256) {
            int r = i / 76, c = i % 76;
            dst4[i] = src4[(size_t)r * 4864 + c];
        }
    }

    float2 off2 = ((const float2*)offs)[p];
    float py = __fadd_rn((float)gy, off2.x);
    float px = __fadd_rn((float)gx, off2.y);

    float ymn = py, ymx = py, xmn = px, xmx = px;
    for (int d = 32; d; d >>= 1) {
        ymn = fminf(ymn, __shfl_xor(ymn, d));
        ymx = fmaxf(ymx, __shfl_xor(ymx, d));
        xmn = fminf(xmn, __shfl_xor(xmn, d));
        xmx = fmaxf(xmx, __shfl_xor(xmx, d));
    }
    if ((tid & 63) == 0) {
        int w = tid >> 6;
        sred[w * 4 + 0] = ymn; sred[w * 4 + 1] = ymx;
        sred[w * 4 + 2] = xmn; sred[w * 4 + 3] = xmx;
    }
    __syncthreads();

    ymn = fminf(fminf(sred[0], sred[4]), fminf(sred[8],  sred[12]));
    ymx = fmaxf(fmaxf(sred[1], sred[5]), fmaxf(sred[9],  sred[13]));
    xmn = fminf(fminf(sred[2], sred[6]), fminf(sred[10], sred[14]));
    xmx = fmaxf(fmaxf(sred[3], sred[7]), fmaxf(sred[11], sred[15]));

    float L = INFINITY, U = INFINITY;
    bool valid = false;
    if (tid < KEEP) {
        float4 c4 = sc[tid];
        valid = (c4.w > 0.f);
        if (valid) {
            float dyl = fmaxf(fmaxf(ymn - c4.x, c4.x - ymx), 0.f);
            float dxl = fmaxf(fmaxf(xmn - c4.y, c4.y - xmx), 0.f);
            L = dyl * dyl + dxl * dxl;
            float dyu = fmaxf(fabsf(c4.x - ymn), fabsf(c4.x - ymx));
            float dxu = fmaxf(fabsf(c4.y - xmn), fabsf(c4.y - xmx));
            U = dyu * dyu + dxu * dxu;
        }
    }
    float u = U;
    for (int d = 32; d; d >>= 1) u = fminf(u, __shfl_xor(u, d));
    if ((tid & 63) == 0) ured[tid >> 6] = u;
    __syncthreads();
    float Umin = fminf(fminf(ured[0], ured[1]), fminf(ured[2], ured[3]));

    bool keep = valid && (L <= Umin + 8.0f);   // margin 8 >> rounding slop ~2
    u64 mask = __ballot(keep);
    int lane = tid & 63;
    int prefix = __popcll(mask & ((1ull << lane) - 1ull));
    if (lane == 0) wcnt[tid >> 6] = __popcll(mask);
    __syncthreads();
    int base = (tid >> 6) == 1 ? wcnt[0] : 0;
    if (keep) { skept[base + prefix] = sc[tid]; skidx[base + prefix] = tid; }
    if (tid == 0) s_nkept = wcnt[0] + wcnt[1];
    __syncthreads();

    const float* l = slog + tid * NCLS;
    float best = l[0];
    int cls = 0;
#pragma unroll
    for (int c = 1; c < NCLS; c++) {
        float v = l[c];
        if (v > best) { best = v; cls = c; }
    }
    bool thing = false;
    for (int j = 0; j < n_thing; j++) thing = thing || (cls == sids[j]);

    float b = __fadd_rn(__fmul_rn(py, py), __fmul_rn(px, px));

    float bestd = INFINITY;
    int bi = -1;
    int nk = s_nkept;
    for (int k = 0; k < nk; k++) {
        float4 c4 = skept[k];
        // replicate f32 gemm: m = fma(cx,px, rn(cy*py)); d2 = rn(rn(a-2m)+b)
        float m  = __fmaf_rn(c4.y, px, __fmul_rn(c4.x, py));
        float d2 = __fadd_rn(__fsub_rn(c4.z, __fadd_rn(m, m)), b);
        if (d2 < bestd) { bestd = d2; bi = k; }
    }

    float inst, smap;
    if (bi < 0) { inst = thing ? 1.f : 0.f; smap = 0.f; }
    else {
        inst = thing ? (float)(skidx[bi] + 1) : 0.f;
        smap = thing ? skept[bi].w : 0.f;
    }
    out[p] = inst;
    out[2 * HWSZ + p] = smap;
    out[3 * HWSZ + p] = (float)cls;
}

extern "C" void kernel_launch(void* const* d_in, const int* in_sizes, int n_in,
                              void* d_out, int out_size, void* d_ws, size_t ws_size,
                              hipStream_t stream) {
    const float* logits = (const float*)d_in[0];
    const float* heat   = (const float*)d_in[1];
    const float* offs   = (const float*)d_in[2];
    const int*   tids   = (const int*)d_in[3];
    int n_thing = in_sizes[3];
    if (n_thing > 32) n_thing = 32;

    float* out = (float*)d_out;
    char* ws = (char*)d_ws;
    // layout: blkcnt[512] @0 | gcnt[16] @2048 | centers @4096 | gtop @8192 (24KB) | keys @32768
    int* blkcnt = (int*)ws;
    int* gcnt = (int*)(ws + 2048);
    float4* centers = (float4*)(ws + 4096);
    u64* gtop = (u64*)(ws + 8192);
    long long avail = (long long)ws_size - 32768;
    int maxpb = (int)(avail / (NBLK * 8));
    if (maxpb > 120) maxpb = 120;
    if (maxpb < 16) maxpb = 16;
    u64* keys = (u64*)(ws + 32768);   // transposed [maxpb][512]

    nms_kernel<<<dim3(NBLK), dim3(256), 0, stream>>>(heat, out + HWSZ, keys, blkcnt, maxpb);
    reduce_kernel<<<dim3(NRED), dim3(256), 0, stream>>>(keys, blkcnt, maxpb, gtop, gcnt);
    select_kernel<<<dim3(1), dim3(256), 0, stream>>>(gtop, gcnt, centers);
    assign_kernel<<<dim3((WW / 16) * (HH / 16)), dim3(256), 0, stream>>>(logits, offs, tids, n_thing, centers, out);
}